// Round 6
// baseline (151.402 us; speedup 1.0000x reference)
//
#include <hip/hip_runtime.h>

// PositionalCharacterLevelWordSparse:
//   rows = B*W = 65536, L = 16 chars/row, D = 512 + 16 = 528 bins/row.
//   out[row, tok[row,c]]       += (tok != 0)
//   out[row, 512 + pos[row,c]] += (tok != 0)
// Strategy: per-block float LDS histograms, coalesced nontemporal float4
// writes. Write-bound: ~138 MB out, ~8 MB in.
//
// vs R2: 16 rows/block, 512 threads (LDS 33.8 KB -> 4 blocks/CU -> still
// 2048 thr/CU = 100% occupancy). Halves block count (4096) and barriers
// per byte; doubles store work per block to amortize the two barriers.
// (R3/R4/R5 benches never ran - GPU acquisition timeouts; resubmitting.)

constexpr int NUM_EMB = 512;
constexpr int MAX_POS = 16;
constexpr int D = NUM_EMB + MAX_POS;   // 528
constexpr int L = 16;
constexpr int ROWS_PER_BLOCK = 16;
constexpr int THREADS = 512;
constexpr int SCATTER = ROWS_PER_BLOCK * L;          // 256
constexpr int HIST = ROWS_PER_BLOCK * D;             // 8448 floats = 33.8 KB
constexpr int HIST4 = HIST / 4;                      // 2112 float4
constexpr int FULL_IT = HIST4 / THREADS;             // 4
constexpr int REM = HIST4 - FULL_IT * THREADS;       // 64

typedef float v4f __attribute__((ext_vector_type(4)));

__global__ __launch_bounds__(THREADS)
void pcls_hist_kernel(const int* __restrict__ tok,
                      const int* __restrict__ pos,
                      float* __restrict__ out) {
    __shared__ float hist[HIST];

    const int tid = threadIdx.x;
    const long long row_base = (long long)blockIdx.x * ROWS_PER_BLOCK;

    // Issue the input loads FIRST: their latency overlaps the LDS zeroing.
    int t = 0, p = 0;
    if (tid < SCATTER) {
        const long long g = row_base * L + tid;
        t = tok[g];
        p = pos[g];
    }

    // Zero the row-histograms (float4-wide, unrolled).
    v4f* h4 = reinterpret_cast<v4f*>(hist);
    #pragma unroll
    for (int i = 0; i < FULL_IT; ++i)
        h4[tid + i * THREADS] = (v4f)0.0f;
    if (tid < REM)
        h4[tid + FULL_IT * THREADS] = (v4f)0.0f;
    __syncthreads();

    // Scatter: first 256 threads each own one (row, char) slot. Mask BOTH adds.
    if (tid < SCATTER && t != 0) {
        const int r = tid >> 4;            // tid / L
        atomicAdd(&hist[r * D + t], 1.0f);          // ds_add_f32
        atomicAdd(&hist[r * D + NUM_EMB + p], 1.0f);
    }
    __syncthreads();

    // Stream out: 16 rows * 528 floats contiguous per block, nontemporal.
    v4f* out4 = reinterpret_cast<v4f*>(out + row_base * D);
    #pragma unroll
    for (int i = 0; i < FULL_IT; ++i)
        __builtin_nontemporal_store(h4[tid + i * THREADS], &out4[tid + i * THREADS]);
    if (tid < REM)
        __builtin_nontemporal_store(h4[tid + FULL_IT * THREADS],
                                    &out4[tid + FULL_IT * THREADS]);
}

extern "C" void kernel_launch(void* const* d_in, const int* in_sizes, int n_in,
                              void* d_out, int out_size, void* d_ws, size_t ws_size,
                              hipStream_t stream) {
    const int* tok = (const int*)d_in[0];
    const int* pos = (const int*)d_in[1];
    float* out = (float*)d_out;

    const int n_rows = in_sizes[0] / L;              // 65536
    const int grid = n_rows / ROWS_PER_BLOCK;        // 4096

    pcls_hist_kernel<<<grid, THREADS, 0, stream>>>(tok, pos, out);
}